// Round 2
// baseline (771.874 us; speedup 1.0000x reference)
//
#include <hip/hip_runtime.h>

typedef short bf16x8 __attribute__((ext_vector_type(8)));
typedef float floatx4 __attribute__((ext_vector_type(4)));

// ---------- bf16 helpers (bit-level, RNE) ----------
__device__ __forceinline__ float bf2f(unsigned short u) {
    return __uint_as_float(((unsigned)u) << 16);
}
__device__ __forceinline__ unsigned short f2bf(float f) {
    unsigned u = __float_as_uint(f);
    unsigned rnd = 0x7fffu + ((u >> 16) & 1u);
    return (unsigned short)((u + rnd) >> 16);
}

// ---------- async global->LDS 16B ----------
__device__ __forceinline__ void async16(const unsigned short* g, unsigned short* l) {
    __builtin_amdgcn_global_load_lds(
        (const __attribute__((address_space(1))) unsigned int*)g,
        (__attribute__((address_space(3))) unsigned int*)l,
        16, 0, 0);
}

// ---------- fp32 -> bf16 batch convert ----------
struct CvtArgs {
    const float* src[12];
    unsigned short* dst[12];
    int n4[12];
};

__global__ __launch_bounds__(256) void cvt_kernel(CvtArgs a) {
    int t = blockIdx.y;
    int n4 = a.n4[t];
    const float4* s = (const float4*)a.src[t];
    unsigned short* d = a.dst[t];
    int stride = gridDim.x * blockDim.x;
    for (int i = blockIdx.x * blockDim.x + threadIdx.x; i < n4; i += stride) {
        float4 v = s[i];
        ushort4 o;
        o.x = f2bf(v.x); o.y = f2bf(v.y); o.z = f2bf(v.z); o.w = f2bf(v.w);
        ((ushort4*)d)[i] = o;
    }
}

// ---------- GEMM: C[M,N] = A[M,K] @ B[N,K]^T * scale (+ bias[N]) ----------
// A, B bf16 row-major. Templated tile BMxBN (BK=32), 4 waves in 2x2, each wave
// (BM/2)x(BN/2) via (MI x MJ) MFMA 16x16x32 ops.
// LDS tiles in MFMA fragment order: position p holds X[(p>>6)*16 + (p&15)]
// [k0 + ((p>>4)&3)*8 ..+7] -> both global_load_lds staging and ds_read_b128
// fragment reads are lane-linear (conflict-free).
// MINW: min waves/EU for __launch_bounds__ (2 -> >=2 blocks/CU, 4 -> >=4).
template<int BM, int BN, bool BF16_OUT, bool TRANS_OUT, bool HAS_BIAS, int MINW>
__global__ __launch_bounds__(256, MINW) void gemm_bt(
    const unsigned short* __restrict__ A,
    const unsigned short* __restrict__ B,
    const float* __restrict__ bias,
    void* __restrict__ C,
    int M, int N, int K, float scale)
{
    constexpr int BK = 32;
    constexpr int MI = BM / 32;           // MFMA rows per wave (wave tile BM/2)
    constexpr int MJ = BN / 32;           // MFMA cols per wave
    constexpr int CA = (BM * BK / 8) / 256; // staging chunks per thread (A)
    constexpr int CB = (BN * BK / 8) / 256;

    __shared__ __align__(16) unsigned short lA[BM * BK];
    __shared__ __align__(16) unsigned short lB[BN * BK];

    const int tid  = threadIdx.x;
    const int lane = tid & 63;
    const int wave = tid >> 6;
    const int wm   = wave >> 1;   // 0..1
    const int wn   = wave & 1;    // 0..1
    const int quad = lane >> 4;   // 0..3
    const int r16  = lane & 15;

    const int row0 = blockIdx.y * BM;
    const int col0 = blockIdx.x * BN;

    floatx4 acc[MI][MJ] = {};

    const unsigned short* gA[CA];
    const unsigned short* gB[CB];
    unsigned short* lAp[CA];
    unsigned short* lBp[CB];
    #pragma unroll
    for (int c = 0; c < CA; c++) {
        int p = c * 256 + tid;
        int i = p >> 6, q = (p >> 4) & 3, r = p & 15;
        gA[c] = A + (size_t)(row0 + i * 16 + r) * K + q * 8;
        lAp[c] = lA + p * 8;
    }
    #pragma unroll
    for (int c = 0; c < CB; c++) {
        int p = c * 256 + tid;
        int i = p >> 6, q = (p >> 4) & 3, r = p & 15;
        gB[c] = B + (size_t)(col0 + i * 16 + r) * K + q * 8;
        lBp[c] = lB + p * 8;
    }

    for (int k0 = 0; k0 < K; k0 += BK) {
        #pragma unroll
        for (int c = 0; c < CA; c++) { async16(gA[c], lAp[c]); gA[c] += BK; }
        #pragma unroll
        for (int c = 0; c < CB; c++) { async16(gB[c], lBp[c]); gB[c] += BK; }
        __syncthreads();

        bf16x8 af[MI], bfr[MJ];
        #pragma unroll
        for (int i = 0; i < MI; i++)
            af[i] = *(const bf16x8*)(lA + ((wm * MI + i) * 64 + lane) * 8);
        #pragma unroll
        for (int j = 0; j < MJ; j++)
            bfr[j] = *(const bf16x8*)(lB + ((wn * MJ + j) * 64 + lane) * 8);

        #pragma unroll
        for (int i = 0; i < MI; i++)
            #pragma unroll
            for (int j = 0; j < MJ; j++)
                acc[i][j] = __builtin_amdgcn_mfma_f32_16x16x32_bf16(
                    af[i], bfr[j], acc[i][j], 0, 0, 0);
        __syncthreads();
    }

    float bv[MJ];
    if (HAS_BIAS) {
        #pragma unroll
        for (int j = 0; j < MJ; j++)
            bv[j] = bias[col0 + (wn * MJ + j) * 16 + r16];
    }

    #pragma unroll
    for (int i = 0; i < MI; i++) {
        const int m_base = row0 + (wm * MI + i) * 16 + quad * 4;
        #pragma unroll
        for (int j = 0; j < MJ; j++) {
            const int n = col0 + (wn * MJ + j) * 16 + r16;
            if (TRANS_OUT) {
                // C^T layout [N][M], bf16; 4 consecutive m -> one 8B store
                ushort4 o;
                float v0 = acc[i][j][0] * scale; if (HAS_BIAS) v0 += bv[j];
                float v1 = acc[i][j][1] * scale; if (HAS_BIAS) v1 += bv[j];
                float v2 = acc[i][j][2] * scale; if (HAS_BIAS) v2 += bv[j];
                float v3 = acc[i][j][3] * scale; if (HAS_BIAS) v3 += bv[j];
                o.x = f2bf(v0); o.y = f2bf(v1); o.z = f2bf(v2); o.w = f2bf(v3);
                *(ushort4*)((unsigned short*)C + (size_t)n * M + m_base) = o;
            } else {
                #pragma unroll
                for (int r = 0; r < 4; r++) {
                    float v = acc[i][j][r] * scale;
                    if (HAS_BIAS) v += bv[j];
                    size_t off = (size_t)(m_base + r) * N + n;
                    if (BF16_OUT) ((unsigned short*)C)[off] = f2bf(v);
                    else          ((float*)C)[off] = v;
                }
            }
        }
    }
}

// ---------- row softmax: S[row,0..4095] bf16 -> P bf16, fp32 math ----------
__global__ __launch_bounds__(256) void softmax_kernel(
    const unsigned short* __restrict__ S, unsigned short* __restrict__ P)
{
    const int N = 4096;
    const int row = blockIdx.x;
    const int tid = threadIdx.x;
    const int lane = tid & 63;
    const int wave = tid >> 6;

    const bf16x8* src = (const bf16x8*)(S + (size_t)row * N);
    bf16x8 c0 = src[2 * tid];
    bf16x8 c1 = src[2 * tid + 1];

    float x[16];
    #pragma unroll
    for (int k = 0; k < 8; k++) {
        x[k]     = bf2f((unsigned short)c0[k]);
        x[8 + k] = bf2f((unsigned short)c1[k]);
    }

    float m = -3.4e38f;
    #pragma unroll
    for (int k = 0; k < 16; k++) m = fmaxf(m, x[k]);
    #pragma unroll
    for (int off = 32; off > 0; off >>= 1) m = fmaxf(m, __shfl_xor(m, off));

    __shared__ float redmax[4], redsum[4];
    if (lane == 0) redmax[wave] = m;
    __syncthreads();
    m = fmaxf(fmaxf(redmax[0], redmax[1]), fmaxf(redmax[2], redmax[3]));

    float s = 0.f;
    #pragma unroll
    for (int k = 0; k < 16; k++) { x[k] = __expf(x[k] - m); s += x[k]; }
    #pragma unroll
    for (int off = 32; off > 0; off >>= 1) s += __shfl_xor(s, off);
    if (lane == 0) redsum[wave] = s;
    __syncthreads();
    s = redsum[0] + redsum[1] + redsum[2] + redsum[3];
    const float inv = 1.0f / s;

    bf16x8 o0, o1;
    #pragma unroll
    for (int k = 0; k < 8; k++) {
        o0[k] = (short)f2bf(x[k] * inv);
        o1[k] = (short)f2bf(x[8 + k] * inv);
    }
    bf16x8* dst = (bf16x8*)(P + (size_t)row * N);
    dst[2 * tid]     = o0;
    dst[2 * tid + 1] = o1;
}

// ---------- launch ----------
extern "C" void kernel_launch(void* const* d_in, const int* in_sizes, int n_in,
                              void* d_out, int out_size, void* d_ws, size_t ws_size,
                              hipStream_t stream) {
    (void)in_sizes; (void)n_in; (void)out_size;
    const int NC = 4096, NP = 4096, D = 1024;

    char* ws = (char*)d_ws;
    size_t off = 0;
    auto alloc = [&](size_t b) { size_t o = off; off += (b + 255) & ~(size_t)255; return o; };

    unsigned short* xb[6];
    for (int i = 0; i < 6; i++) xb[i] = (unsigned short*)(ws + alloc((size_t)NC * D * 2));
    unsigned short* wb[6];
    for (int i = 0; i < 6; i++) wb[i] = (unsigned short*)(ws + alloc((size_t)D * D * 2));
    unsigned short* qc  = (unsigned short*)(ws + alloc((size_t)NC * D * 2));
    unsigned short* kc  = (unsigned short*)(ws + alloc((size_t)NC * D * 2));
    unsigned short* qp  = (unsigned short*)(ws + alloc((size_t)NP * D * 2));
    unsigned short* kp  = (unsigned short*)(ws + alloc((size_t)NP * D * 2));
    unsigned short* vcT = (unsigned short*)(ws + alloc((size_t)NC * D * 2)); // [D][NC]
    unsigned short* vpT = (unsigned short*)(ws + alloc((size_t)NP * D * 2)); // [D][NP]
    unsigned short* Sb  = (unsigned short*)(ws + alloc((size_t)4096 * 4096 * 2));
    unsigned short* Pb  = (unsigned short*)(ws + alloc((size_t)4096 * 4096 * 2));

    if (ws_size < off) return; // workspace too small -> clean mismatch, not a fault

    // convert inputs (d_in[0..5]) and weights (d_in[6,8,10,12,14,16]) to bf16
    CvtArgs ca;
    for (int i = 0; i < 6; i++) {
        ca.src[i] = (const float*)d_in[i];
        ca.dst[i] = xb[i];
        ca.n4[i] = NC * D / 4;
    }
    const int widx[6] = {6, 8, 10, 12, 14, 16};
    for (int i = 0; i < 6; i++) {
        ca.src[6 + i] = (const float*)d_in[widx[i]];
        ca.dst[6 + i] = wb[i];
        ca.n4[6 + i] = D * D / 4;
    }
    cvt_kernel<<<dim3(256, 12), 256, 0, stream>>>(ca);

    const dim3 blk(256);
    const float inv_scale = 1.0f / 32.0f; // 1/sqrt(D_OUT)

    // projections: X @ W^T + b.  N=1024 -> 64x64 tiles for 1024 blocks (4/CU).
    const dim3 gproj(D / 64, NC / 64);
    gemm_bt<64, 64, true, false, true, 4><<<gproj, blk, 0, stream>>>(
        xb[0], wb[0], (const float*)d_in[7],  qc,  NC, D, D, 1.0f);
    gemm_bt<64, 64, true, false, true, 4><<<gproj, blk, 0, stream>>>(
        xb[1], wb[1], (const float*)d_in[9],  kc,  NC, D, D, 1.0f);
    gemm_bt<64, 64, true, true,  true, 4><<<gproj, blk, 0, stream>>>(
        xb[2], wb[2], (const float*)d_in[11], vcT, NC, D, D, 1.0f);
    gemm_bt<64, 64, true, false, true, 4><<<gproj, blk, 0, stream>>>(
        xb[3], wb[3], (const float*)d_in[13], qp,  NP, D, D, 1.0f);
    gemm_bt<64, 64, true, false, true, 4><<<gproj, blk, 0, stream>>>(
        xb[4], wb[4], (const float*)d_in[15], kp,  NP, D, D, 1.0f);
    gemm_bt<64, 64, true, true,  true, 4><<<gproj, blk, 0, stream>>>(
        xb[5], wb[5], (const float*)d_in[17], vpT, NP, D, D, 1.0f);

    float* out_c = (float*)d_out;                       // comp_fused [NC, D]
    float* out_p = (float*)d_out + (size_t)NC * D;      // prot_fused [NP, D]

    const dim3 gscore(4096 / 128, 4096 / 128);          // 1024 blocks
    const dim3 gpv(D / 64, 4096 / 64);                  // 1024 blocks

    // side 1: compound attends protein
    gemm_bt<128, 128, true, false, false, 2><<<gscore, blk, 0, stream>>>(
        qc, kp, nullptr, Sb, NC, NP, D, inv_scale);
    softmax_kernel<<<dim3(NC), blk, 0, stream>>>(Sb, Pb);
    gemm_bt<64, 64, false, false, false, 4><<<gpv, blk, 0, stream>>>(
        Pb, vpT, nullptr, out_c, NC, D, NP, 1.0f);

    // side 2: protein attends compound
    gemm_bt<128, 128, true, false, false, 2><<<gscore, blk, 0, stream>>>(
        qp, kc, nullptr, Sb, NP, NC, D, inv_scale);
    softmax_kernel<<<dim3(NP), blk, 0, stream>>>(Sb, Pb);
    gemm_bt<64, 64, false, false, false, 4><<<gpv, blk, 0, stream>>>(
        Pb, vcT, nullptr, out_p, NP, D, NC, 1.0f);
}

// Round 3
// 739.107 us; speedup vs baseline: 1.0443x; 1.0443x over previous
//
#include <hip/hip_runtime.h>

typedef short bf16x8 __attribute__((ext_vector_type(8)));
typedef float floatx4 __attribute__((ext_vector_type(4)));

// ---------- bf16 helpers (bit-level, RNE) ----------
__device__ __forceinline__ float bf2f(unsigned short u) {
    return __uint_as_float(((unsigned)u) << 16);
}
__device__ __forceinline__ unsigned short f2bf(float f) {
    unsigned u = __float_as_uint(f);
    unsigned rnd = 0x7fffu + ((u >> 16) & 1u);
    return (unsigned short)((u + rnd) >> 16);
}

// ---------- async global->LDS 16B ----------
__device__ __forceinline__ void async16(const unsigned short* g, unsigned short* l) {
    __builtin_amdgcn_global_load_lds(
        (const __attribute__((address_space(1))) unsigned int*)g,
        (__attribute__((address_space(3))) unsigned int*)l,
        16, 0, 0);
}

// ---------- fp32 -> bf16 batch convert ----------
struct CvtArgs {
    const float* src[12];
    unsigned short* dst[12];
    int n4[12];
};

__global__ __launch_bounds__(256) void cvt_kernel(CvtArgs a) {
    int t = blockIdx.y;
    int n4 = a.n4[t];
    const float4* s = (const float4*)a.src[t];
    unsigned short* d = a.dst[t];
    int stride = gridDim.x * blockDim.x;
    for (int i = blockIdx.x * blockDim.x + threadIdx.x; i < n4; i += stride) {
        float4 v = s[i];
        ushort4 o;
        o.x = f2bf(v.x); o.y = f2bf(v.y); o.z = f2bf(v.z); o.w = f2bf(v.w);
        ((ushort4*)d)[i] = o;
    }
}

// ---------- batched GEMM: C[M,N] = A[M,K] @ B[N,K]^T * scale (+ bias[N]) ----
// blockIdx.z selects the sub-problem (same M,N,K across the batch).
// LDS fragment-order layout: position p = (i*KQ + q)*16 + r holds
// X[i*16 + r][k0 + q*8 .. +7], KQ = BK/8.  Staging (global_load_lds, 16B,
// lane-linear) and ds_read_b128 fragment reads both map linearly -> no
// conflicts.  4 waves in 2x2; wave tile (BM/2)x(BN/2); NS = BK/32 MFMA
// k-substeps per staged tile.
template<int NB> struct GemmArgs {
    const unsigned short* A[NB];
    const unsigned short* B[NB];
    const float* bias[NB];
    void* C[NB];
    int trans[NB];
};

template<int BM, int BN, int BK, int NB, bool BF16_OUT, bool HAS_BIAS,
         bool ALLOW_TRANS, int MINW>
__global__ __launch_bounds__(256, MINW) void gemm_batched(
    GemmArgs<NB> args, int M, int N, int K, float scale)
{
    constexpr int KQ = BK / 8;            // 8-elem k-chunks per staged tile
    constexpr int NS = BK / 32;           // MFMA k-substeps
    constexpr int MI = BM / 32;           // MFMA row tiles per wave
    constexpr int MJ = BN / 32;           // MFMA col tiles per wave
    constexpr int CA = (BM * BK / 8) / 256;
    constexpr int CB = (BN * BK / 8) / 256;

    __shared__ __align__(16) unsigned short lA[BM * BK];
    __shared__ __align__(16) unsigned short lB[BN * BK];

    const int z = blockIdx.z;
    const unsigned short* __restrict__ A = args.A[z];
    const unsigned short* __restrict__ B = args.B[z];

    const int tid  = threadIdx.x;
    const int lane = tid & 63;
    const int wave = tid >> 6;
    const int wm   = wave >> 1;   // 0..1
    const int wn   = wave & 1;    // 0..1
    const int quad = lane >> 4;   // 0..3
    const int r16  = lane & 15;

    const int row0 = blockIdx.y * BM;
    const int col0 = blockIdx.x * BN;

    floatx4 acc[MI][MJ] = {};

    const unsigned short* gA[CA];
    const unsigned short* gB[CB];
    unsigned short* lAp[CA];
    unsigned short* lBp[CB];
    #pragma unroll
    for (int c = 0; c < CA; c++) {
        int p = c * 256 + tid;
        int i = p / (KQ * 16), q = (p >> 4) % KQ, r = p & 15;
        gA[c] = A + (size_t)(row0 + i * 16 + r) * K + q * 8;
        lAp[c] = lA + p * 8;
    }
    #pragma unroll
    for (int c = 0; c < CB; c++) {
        int p = c * 256 + tid;
        int i = p / (KQ * 16), q = (p >> 4) % KQ, r = p & 15;
        gB[c] = B + (size_t)(col0 + i * 16 + r) * K + q * 8;
        lBp[c] = lB + p * 8;
    }

    for (int k0 = 0; k0 < K; k0 += BK) {
        #pragma unroll
        for (int c = 0; c < CA; c++) { async16(gA[c], lAp[c]); gA[c] += BK; }
        #pragma unroll
        for (int c = 0; c < CB; c++) { async16(gB[c], lBp[c]); gB[c] += BK; }
        __syncthreads();

        #pragma unroll
        for (int s = 0; s < NS; s++) {
            bf16x8 af[MI], bfr[MJ];
            #pragma unroll
            for (int i = 0; i < MI; i++)
                af[i] = *(const bf16x8*)(lA +
                    (((wm * MI + i) * KQ + s * 4 + quad) * 16 + r16) * 8);
            #pragma unroll
            for (int j = 0; j < MJ; j++)
                bfr[j] = *(const bf16x8*)(lB +
                    (((wn * MJ + j) * KQ + s * 4 + quad) * 16 + r16) * 8);

            #pragma unroll
            for (int i = 0; i < MI; i++)
                #pragma unroll
                for (int j = 0; j < MJ; j++)
                    acc[i][j] = __builtin_amdgcn_mfma_f32_16x16x32_bf16(
                        af[i], bfr[j], acc[i][j], 0, 0, 0);
        }
        __syncthreads();
    }

    float bv[MJ];
    if (HAS_BIAS) {
        #pragma unroll
        for (int j = 0; j < MJ; j++)
            bv[j] = args.bias[z][col0 + (wn * MJ + j) * 16 + r16];
    }

    void* C = args.C[z];
    const bool do_trans = ALLOW_TRANS && args.trans[z];

    #pragma unroll
    for (int i = 0; i < MI; i++) {
        const int m_base = row0 + (wm * MI + i) * 16 + quad * 4;
        #pragma unroll
        for (int j = 0; j < MJ; j++) {
            const int n = col0 + (wn * MJ + j) * 16 + r16;
            if (ALLOW_TRANS && do_trans) {
                // C^T layout [N][M], bf16; 4 consecutive m -> one 8B store
                ushort4 o;
                float v0 = acc[i][j][0] * scale; if (HAS_BIAS) v0 += bv[j];
                float v1 = acc[i][j][1] * scale; if (HAS_BIAS) v1 += bv[j];
                float v2 = acc[i][j][2] * scale; if (HAS_BIAS) v2 += bv[j];
                float v3 = acc[i][j][3] * scale; if (HAS_BIAS) v3 += bv[j];
                o.x = f2bf(v0); o.y = f2bf(v1); o.z = f2bf(v2); o.w = f2bf(v3);
                *(ushort4*)((unsigned short*)C + (size_t)n * M + m_base) = o;
            } else {
                #pragma unroll
                for (int r = 0; r < 4; r++) {
                    float v = acc[i][j][r] * scale;
                    if (HAS_BIAS) v += bv[j];
                    size_t off = (size_t)(m_base + r) * N + n;
                    if (BF16_OUT) ((unsigned short*)C)[off] = f2bf(v);
                    else          ((float*)C)[off] = v;
                }
            }
        }
    }
}

// ---------- row softmax, in-place: S[row,0..4095] bf16, fp32 math ----------
struct SmArgs { unsigned short* S[2]; };

__global__ __launch_bounds__(256) void softmax_kernel(SmArgs a) {
    const int N = 4096;
    unsigned short* S = a.S[blockIdx.y];
    const int row = blockIdx.x;
    const int tid = threadIdx.x;
    const int lane = tid & 63;
    const int wave = tid >> 6;

    bf16x8* ptr = (bf16x8*)(S + (size_t)row * N);
    bf16x8 c0 = ptr[2 * tid];
    bf16x8 c1 = ptr[2 * tid + 1];

    float x[16];
    #pragma unroll
    for (int k = 0; k < 8; k++) {
        x[k]     = bf2f((unsigned short)c0[k]);
        x[8 + k] = bf2f((unsigned short)c1[k]);
    }

    float m = -3.4e38f;
    #pragma unroll
    for (int k = 0; k < 16; k++) m = fmaxf(m, x[k]);
    #pragma unroll
    for (int off = 32; off > 0; off >>= 1) m = fmaxf(m, __shfl_xor(m, off));

    __shared__ float redmax[4], redsum[4];
    if (lane == 0) redmax[wave] = m;
    __syncthreads();
    m = fmaxf(fmaxf(redmax[0], redmax[1]), fmaxf(redmax[2], redmax[3]));

    float s = 0.f;
    #pragma unroll
    for (int k = 0; k < 16; k++) { x[k] = __expf(x[k] - m); s += x[k]; }
    #pragma unroll
    for (int off = 32; off > 0; off >>= 1) s += __shfl_xor(s, off);
    if (lane == 0) redsum[wave] = s;
    __syncthreads();
    s = redsum[0] + redsum[1] + redsum[2] + redsum[3];
    const float inv = 1.0f / s;

    bf16x8 o0, o1;
    #pragma unroll
    for (int k = 0; k < 8; k++) {
        o0[k] = (short)f2bf(x[k] * inv);
        o1[k] = (short)f2bf(x[8 + k] * inv);
    }
    ptr[2 * tid]     = o0;
    ptr[2 * tid + 1] = o1;
}

// ---------- launch ----------
extern "C" void kernel_launch(void* const* d_in, const int* in_sizes, int n_in,
                              void* d_out, int out_size, void* d_ws, size_t ws_size,
                              hipStream_t stream) {
    (void)in_sizes; (void)n_in; (void)out_size;
    const int NC = 4096, NP = 4096, D = 1024;

    char* ws = (char*)d_ws;
    size_t off = 0;
    auto alloc = [&](size_t b) { size_t o = off; off += (b + 255) & ~(size_t)255; return o; };

    unsigned short* xb[6];
    for (int i = 0; i < 6; i++) xb[i] = (unsigned short*)(ws + alloc((size_t)NC * D * 2));
    unsigned short* wb[6];
    for (int i = 0; i < 6; i++) wb[i] = (unsigned short*)(ws + alloc((size_t)D * D * 2));
    unsigned short* qc  = (unsigned short*)(ws + alloc((size_t)NC * D * 2));
    unsigned short* kc  = (unsigned short*)(ws + alloc((size_t)NC * D * 2));
    unsigned short* qp  = (unsigned short*)(ws + alloc((size_t)NP * D * 2));
    unsigned short* kp  = (unsigned short*)(ws + alloc((size_t)NP * D * 2));
    unsigned short* vcT = (unsigned short*)(ws + alloc((size_t)NC * D * 2)); // [D][NC]
    unsigned short* vpT = (unsigned short*)(ws + alloc((size_t)NP * D * 2)); // [D][NP]
    unsigned short* Sb1 = (unsigned short*)(ws + alloc((size_t)4096 * 4096 * 2));
    unsigned short* Sb2 = (unsigned short*)(ws + alloc((size_t)4096 * 4096 * 2));

    if (ws_size < off) return; // workspace too small -> clean mismatch, not a fault

    // convert inputs (d_in[0..5]) and weights (d_in[6,8,10,12,14,16]) to bf16
    CvtArgs ca;
    for (int i = 0; i < 6; i++) {
        ca.src[i] = (const float*)d_in[i];
        ca.dst[i] = xb[i];
        ca.n4[i] = NC * D / 4;
    }
    const int widx[6] = {6, 8, 10, 12, 14, 16};
    for (int i = 0; i < 6; i++) {
        ca.src[6 + i] = (const float*)d_in[widx[i]];
        ca.dst[6 + i] = wb[i];
        ca.n4[6 + i] = D * D / 4;
    }
    cvt_kernel<<<dim3(256, 12), 256, 0, stream>>>(ca);

    const dim3 blk(256);
    const float inv_scale = 1.0f / 32.0f; // 1/sqrt(D_OUT)

    float* out_c = (float*)d_out;                       // comp_fused [NC, D]
    float* out_p = (float*)d_out + (size_t)NC * D;      // prot_fused [NP, D]

    // --- 6 projections, one dispatch: X @ W^T + b, 64x64 tile, BK=128 ---
    {
        GemmArgs<6> ga;
        unsigned short* outs[6] = {qc, kc, vcT, qp, kp, vpT};
        const int bidx[6] = {7, 9, 11, 13, 15, 17};
        for (int i = 0; i < 6; i++) {
            ga.A[i] = xb[i];
            ga.B[i] = wb[i];
            ga.bias[i] = (const float*)d_in[bidx[i]];
            ga.C[i] = outs[i];
            ga.trans[i] = (i == 2 || i == 5);   // v projections -> transposed
        }
        gemm_batched<64, 64, 128, 6, true, true, true, 4>
            <<<dim3(D / 64, NC / 64, 6), blk, 0, stream>>>(ga, NC, D, D, 1.0f);
    }

    // --- 2 score GEMMs, one dispatch: 128x128 tile, BK=64 ---
    {
        GemmArgs<2> ga;
        ga.A[0] = qc; ga.B[0] = kp; ga.C[0] = Sb1;
        ga.A[1] = qp; ga.B[1] = kc; ga.C[1] = Sb2;
        ga.bias[0] = ga.bias[1] = nullptr;
        ga.trans[0] = ga.trans[1] = 0;
        gemm_batched<128, 128, 64, 2, true, false, false, 3>
            <<<dim3(4096 / 128, 4096 / 128, 2), blk, 0, stream>>>(
                ga, 4096, 4096, D, inv_scale);
    }

    // --- 2 softmaxes, one dispatch, in-place ---
    {
        SmArgs sa; sa.S[0] = Sb1; sa.S[1] = Sb2;
        softmax_kernel<<<dim3(4096, 2), blk, 0, stream>>>(sa);
    }

    // --- 2 PV GEMMs, one dispatch: 64x64 tile, BK=128, fp32 out ---
    {
        GemmArgs<2> ga;
        ga.A[0] = Sb1; ga.B[0] = vpT; ga.C[0] = out_c;
        ga.A[1] = Sb2; ga.B[1] = vcT; ga.C[1] = out_p;
        ga.bias[0] = ga.bias[1] = nullptr;
        ga.trans[0] = ga.trans[1] = 0;
        gemm_batched<64, 64, 128, 2, false, false, false, 4>
            <<<dim3(D / 64, 4096 / 64, 2), blk, 0, stream>>>(
                ga, 4096, D, 4096, 1.0f);
    }
}

// Round 4
// 597.052 us; speedup vs baseline: 1.2928x; 1.2379x over previous
//
#include <hip/hip_runtime.h>

typedef unsigned short ushort_t;
typedef short bf16x8 __attribute__((ext_vector_type(8)));
typedef float floatx4 __attribute__((ext_vector_type(4)));

// ---------- bf16 helpers (bit-level, RNE) ----------
__device__ __forceinline__ float bf2f(ushort_t u) {
    return __uint_as_float(((unsigned)u) << 16);
}
__device__ __forceinline__ ushort_t f2bf(float f) {
    unsigned u = __float_as_uint(f);
    unsigned rnd = 0x7fffu + ((u >> 16) & 1u);
    return (ushort_t)((u + rnd) >> 16);
}

// ---------- batched GEMM: C[M,N] = A[M,K] @ B[N,K]^T * scale (+ bias[N]) ----
// VGPR-staged, double-buffered LDS pipeline (cp.async-style): loads for tile
// t+1 issue as plain global_load_dwordx4 before the MFMA phase on tile t; the
// compiler's vmcnt wait lands at the ds_write AFTER the MFMAs, so load latency
// overlaps compute and many requests stay in flight (vs global_load_lds +
// vmcnt(0) barrier drain which serialized every iteration at ~1.3 TB/s).
// A32/B32: source is fp32, converted to bf16 at ds_write time (fuses the
// cvt pass into the GEMM).
// LDS fragment order: chunk p = (i*4+q)*16+r holds X[i*16+r][k0+q*8..+7];
// both staging writes and ds_read_b128 fragment reads are lane-linear.
template<int NB> struct GemmArgs {
    const void* A[NB];
    const void* B[NB];
    const float* bias[NB];
    void* C[NB];
    int trans[NB];
};

template<int BM, int BN, int NB, bool A32, bool B32, bool BF16_OUT,
         bool HAS_BIAS, bool ALLOW_TRANS, int MINW>
__global__ __launch_bounds__(256, MINW) void gemm_db(
    GemmArgs<NB> args, int M, int N, int K, float scale)
{
    constexpr int BK = 32;
    constexpr int MI = BM / 32;      // MFMA row tiles per wave (2x2 waves)
    constexpr int MJ = BN / 32;
    constexpr int CA = BM / 64;      // staging chunks per thread
    constexpr int CB = BN / 64;

    __shared__ __align__(16) ushort_t lA[2][BM * BK];
    __shared__ __align__(16) ushort_t lB[2][BN * BK];

    const int z = blockIdx.z;
    const char* __restrict__ Ab = (const char*)args.A[z];
    const char* __restrict__ Bb = (const char*)args.B[z];

    const int tid  = threadIdx.x;
    const int lane = tid & 63;
    const int wave = tid >> 6;
    const int wm   = wave >> 1;
    const int wn   = wave & 1;
    const int quad = lane >> 4;
    const int r16  = lane & 15;

    const int row0 = blockIdx.y * BM;
    const int col0 = blockIdx.x * BN;

    floatx4 acc[MI][MJ] = {};

    // per-chunk global base pointers (byte), element offset (row)*K + q*8
    const char* gA[CA];
    const char* gB[CB];
    #pragma unroll
    for (int c = 0; c < CA; c++) {
        int p = c * 256 + tid;
        int i = p >> 6, q = (p >> 4) & 3, r = p & 15;
        size_t eoff = (size_t)(row0 + i * 16 + r) * K + q * 8;
        gA[c] = Ab + eoff * (A32 ? 4 : 2);
    }
    #pragma unroll
    for (int c = 0; c < CB; c++) {
        int p = c * 256 + tid;
        int i = p >> 6, q = (p >> 4) & 3, r = p & 15;
        size_t eoff = (size_t)(col0 + i * 16 + r) * K + q * 8;
        gB[c] = Bb + eoff * (B32 ? 4 : 2);
    }

    // staging registers
    float4 rAf[CA][2]; uint4 rAu[CA];
    float4 rBf[CB][2]; uint4 rBu[CB];

    auto loadA = [&]() {
        #pragma unroll
        for (int c = 0; c < CA; c++) {
            if constexpr (A32) {
                rAf[c][0] = *(const float4*)(gA[c]);
                rAf[c][1] = *(const float4*)(gA[c] + 16);
                gA[c] += BK * 4;
            } else {
                rAu[c] = *(const uint4*)(gA[c]);
                gA[c] += BK * 2;
            }
        }
    };
    auto loadB = [&]() {
        #pragma unroll
        for (int c = 0; c < CB; c++) {
            if constexpr (B32) {
                rBf[c][0] = *(const float4*)(gB[c]);
                rBf[c][1] = *(const float4*)(gB[c] + 16);
                gB[c] += BK * 4;
            } else {
                rBu[c] = *(const uint4*)(gB[c]);
                gB[c] += BK * 2;
            }
        }
    };
    auto writeA = [&](int buf) {
        #pragma unroll
        for (int c = 0; c < CA; c++) {
            bf16x8 v;
            if constexpr (A32) {
                v[0] = (short)f2bf(rAf[c][0].x); v[1] = (short)f2bf(rAf[c][0].y);
                v[2] = (short)f2bf(rAf[c][0].z); v[3] = (short)f2bf(rAf[c][0].w);
                v[4] = (short)f2bf(rAf[c][1].x); v[5] = (short)f2bf(rAf[c][1].y);
                v[6] = (short)f2bf(rAf[c][1].z); v[7] = (short)f2bf(rAf[c][1].w);
            } else {
                v = *(const bf16x8*)&rAu[c];
            }
            *(bf16x8*)(&lA[buf][(c * 256 + tid) * 8]) = v;
        }
    };
    auto writeB = [&](int buf) {
        #pragma unroll
        for (int c = 0; c < CB; c++) {
            bf16x8 v;
            if constexpr (B32) {
                v[0] = (short)f2bf(rBf[c][0].x); v[1] = (short)f2bf(rBf[c][0].y);
                v[2] = (short)f2bf(rBf[c][0].z); v[3] = (short)f2bf(rBf[c][0].w);
                v[4] = (short)f2bf(rBf[c][1].x); v[5] = (short)f2bf(rBf[c][1].y);
                v[6] = (short)f2bf(rBf[c][1].z); v[7] = (short)f2bf(rBf[c][1].w);
            } else {
                v = *(const bf16x8*)&rBu[c];
            }
            *(bf16x8*)(&lB[buf][(c * 256 + tid) * 8]) = v;
        }
    };

    const int T = K / BK;

    // prologue: tile 0
    loadA(); loadB();
    writeA(0); writeB(0);
    __syncthreads();

    for (int t = 0; t < T; ++t) {
        const int cur = t & 1;
        const bool more = (t + 1 < T);
        if (more) { loadA(); loadB(); }   // in flight during MFMA phase

        bf16x8 af[MI], bfr[MJ];
        #pragma unroll
        for (int i = 0; i < MI; i++)
            af[i] = *(const bf16x8*)(&lA[cur][((wm * MI + i) * 64 + lane) * 8]);
        #pragma unroll
        for (int j = 0; j < MJ; j++)
            bfr[j] = *(const bf16x8*)(&lB[cur][((wn * MJ + j) * 64 + lane) * 8]);

        #pragma unroll
        for (int i = 0; i < MI; i++)
            #pragma unroll
            for (int j = 0; j < MJ; j++)
                acc[i][j] = __builtin_amdgcn_mfma_f32_16x16x32_bf16(
                    af[i], bfr[j], acc[i][j], 0, 0, 0);

        if (more) { writeA(cur ^ 1); writeB(cur ^ 1); }  // vmcnt wait lands here
        __syncthreads();
    }

    float bv[MJ];
    if (HAS_BIAS) {
        #pragma unroll
        for (int j = 0; j < MJ; j++)
            bv[j] = args.bias[z][col0 + (wn * MJ + j) * 16 + r16];
    }

    void* C = args.C[z];
    const bool do_trans = ALLOW_TRANS && args.trans[z];

    #pragma unroll
    for (int i = 0; i < MI; i++) {
        const int m_base = row0 + (wm * MI + i) * 16 + quad * 4;
        #pragma unroll
        for (int j = 0; j < MJ; j++) {
            const int n = col0 + (wn * MJ + j) * 16 + r16;
            if (ALLOW_TRANS && do_trans) {
                // C^T layout [N][M], bf16; 4 consecutive m -> one 8B store
                ushort4 o;
                float v0 = acc[i][j][0] * scale; if (HAS_BIAS) v0 += bv[j];
                float v1 = acc[i][j][1] * scale; if (HAS_BIAS) v1 += bv[j];
                float v2 = acc[i][j][2] * scale; if (HAS_BIAS) v2 += bv[j];
                float v3 = acc[i][j][3] * scale; if (HAS_BIAS) v3 += bv[j];
                o.x = f2bf(v0); o.y = f2bf(v1); o.z = f2bf(v2); o.w = f2bf(v3);
                *(ushort4*)((ushort_t*)C + (size_t)n * M + m_base) = o;
            } else {
                #pragma unroll
                for (int r = 0; r < 4; r++) {
                    float v = acc[i][j][r] * scale;
                    if (HAS_BIAS) v += bv[j];
                    size_t off = (size_t)(m_base + r) * N + n;
                    if (BF16_OUT) ((ushort_t*)C)[off] = f2bf(v);
                    else          ((float*)C)[off] = v;
                }
            }
        }
    }
}

// ---------- row softmax, in-place: S[row,0..4095] bf16, fp32 math ----------
struct SmArgs { ushort_t* S[2]; };

__global__ __launch_bounds__(256) void softmax_kernel(SmArgs a) {
    const int N = 4096;
    ushort_t* S = a.S[blockIdx.y];
    const int row = blockIdx.x;
    const int tid = threadIdx.x;
    const int lane = tid & 63;
    const int wave = tid >> 6;

    bf16x8* ptr = (bf16x8*)(S + (size_t)row * N);
    bf16x8 c0 = ptr[2 * tid];
    bf16x8 c1 = ptr[2 * tid + 1];

    float x[16];
    #pragma unroll
    for (int k = 0; k < 8; k++) {
        x[k]     = bf2f((ushort_t)c0[k]);
        x[8 + k] = bf2f((ushort_t)c1[k]);
    }

    float m = -3.4e38f;
    #pragma unroll
    for (int k = 0; k < 16; k++) m = fmaxf(m, x[k]);
    #pragma unroll
    for (int off = 32; off > 0; off >>= 1) m = fmaxf(m, __shfl_xor(m, off));

    __shared__ float redmax[4], redsum[4];
    if (lane == 0) redmax[wave] = m;
    __syncthreads();
    m = fmaxf(fmaxf(redmax[0], redmax[1]), fmaxf(redmax[2], redmax[3]));

    float s = 0.f;
    #pragma unroll
    for (int k = 0; k < 16; k++) { x[k] = __expf(x[k] - m); s += x[k]; }
    #pragma unroll
    for (int off = 32; off > 0; off >>= 1) s += __shfl_xor(s, off);
    if (lane == 0) redsum[wave] = s;
    __syncthreads();
    s = redsum[0] + redsum[1] + redsum[2] + redsum[3];
    const float inv = 1.0f / s;

    bf16x8 o0, o1;
    #pragma unroll
    for (int k = 0; k < 8; k++) {
        o0[k] = (short)f2bf(x[k] * inv);
        o1[k] = (short)f2bf(x[8 + k] * inv);
    }
    ptr[2 * tid]     = o0;
    ptr[2 * tid + 1] = o1;
}

// ---------- launch ----------
extern "C" void kernel_launch(void* const* d_in, const int* in_sizes, int n_in,
                              void* d_out, int out_size, void* d_ws, size_t ws_size,
                              hipStream_t stream) {
    (void)in_sizes; (void)n_in; (void)out_size;
    const int NC = 4096, NP = 4096, D = 1024;

    char* ws = (char*)d_ws;
    size_t off = 0;
    auto alloc = [&](size_t b) { size_t o = off; off += (b + 255) & ~(size_t)255; return o; };

    ushort_t* qc  = (ushort_t*)(ws + alloc((size_t)NC * D * 2));
    ushort_t* kc  = (ushort_t*)(ws + alloc((size_t)NC * D * 2));
    ushort_t* qp  = (ushort_t*)(ws + alloc((size_t)NP * D * 2));
    ushort_t* kp  = (ushort_t*)(ws + alloc((size_t)NP * D * 2));
    ushort_t* vcT = (ushort_t*)(ws + alloc((size_t)NC * D * 2)); // [D][NC]
    ushort_t* vpT = (ushort_t*)(ws + alloc((size_t)NP * D * 2)); // [D][NP]
    ushort_t* Sb1 = (ushort_t*)(ws + alloc((size_t)4096 * 4096 * 2));
    ushort_t* Sb2 = (ushort_t*)(ws + alloc((size_t)4096 * 4096 * 2));

    if (ws_size < off) return;

    const dim3 blk(256);
    const float inv_scale = 1.0f / 32.0f; // 1/sqrt(D_OUT)

    float* out_c = (float*)d_out;                       // comp_fused [NC, D]
    float* out_p = (float*)d_out + (size_t)NC * D;      // prot_fused [NP, D]

    // --- 6 projections, one dispatch: fp32 in (fused cvt), bf16 out ---
    // X @ W^T + b ; 128x128 tile -> grid 8x32x6 = 1536 blocks
    {
        GemmArgs<6> ga;
        ushort_t* outs[6] = {qc, kc, vcT, qp, kp, vpT};
        const int widx[6] = {6, 8, 10, 12, 14, 16};
        const int bidx[6] = {7, 9, 11, 13, 15, 17};
        for (int i = 0; i < 6; i++) {
            ga.A[i] = d_in[i];            // fp32 [4096,1024]
            ga.B[i] = d_in[widx[i]];      // fp32 [1024,1024] (torch layout = B^T)
            ga.bias[i] = (const float*)d_in[bidx[i]];
            ga.C[i] = outs[i];
            ga.trans[i] = (i == 2 || i == 5);   // v projections -> transposed
        }
        gemm_db<128, 128, 6, true, true, true, true, true, 2>
            <<<dim3(D / 128, NC / 128, 6), blk, 0, stream>>>(ga, NC, D, D, 1.0f);
    }

    // --- 2 score GEMMs, one dispatch: bf16, 128x128, grid 32x32x2 ---
    {
        GemmArgs<2> ga;
        ga.A[0] = qc; ga.B[0] = kp; ga.C[0] = Sb1;
        ga.A[1] = qp; ga.B[1] = kc; ga.C[1] = Sb2;
        ga.bias[0] = ga.bias[1] = nullptr;
        ga.trans[0] = ga.trans[1] = 0;
        gemm_db<128, 128, 2, false, false, true, false, false, 2>
            <<<dim3(4096 / 128, 4096 / 128, 2), blk, 0, stream>>>(
                ga, 4096, 4096, D, inv_scale);
    }

    // --- 2 softmaxes, one dispatch, in-place ---
    {
        SmArgs sa; sa.S[0] = Sb1; sa.S[1] = Sb2;
        softmax_kernel<<<dim3(4096, 2), blk, 0, stream>>>(sa);
    }

    // --- 2 PV GEMMs, one dispatch: bf16 in, fp32 out, grid 8x32x2 ---
    {
        GemmArgs<2> ga;
        ga.A[0] = Sb1; ga.B[0] = vpT; ga.C[0] = out_c;
        ga.A[1] = Sb2; ga.B[1] = vcT; ga.C[1] = out_p;
        ga.bias[0] = ga.bias[1] = nullptr;
        ga.trans[0] = ga.trans[1] = 0;
        gemm_db<128, 128, 2, false, false, false, false, false, 2>
            <<<dim3(D / 128, 4096 / 128, 2), blk, 0, stream>>>(
                ga, 4096, D, 4096, 1.0f);
    }
}

// Round 5
// 595.711 us; speedup vs baseline: 1.2957x; 1.0023x over previous
//
#include <hip/hip_runtime.h>

typedef unsigned short ushort_t;
typedef short bf16x8 __attribute__((ext_vector_type(8)));
typedef float floatx4 __attribute__((ext_vector_type(4)));

// ---------- bf16 helpers (bit-level, RNE) ----------
__device__ __forceinline__ float bf2f(ushort_t u) {
    return __uint_as_float(((unsigned)u) << 16);
}
__device__ __forceinline__ ushort_t f2bf(float f) {
    unsigned u = __float_as_uint(f);
    unsigned rnd = 0x7fffu + ((u >> 16) & 1u);
    return (ushort_t)((u + rnd) >> 16);
}

// ---------- batched GEMM: C[M,N] = A[M,K] @ B[N,K]^T * scale (+ bias[N]) ----
// DP-deep software pipeline: DP register staging sets + DP LDS buffers.
// At iter t: issue global loads for tile t+DP (into reg set t%DP, freed by the
// ds_write at iter t-1), MFMA on lds[t%DP], then ds_write reg set (t+1)%DP ->
// lds[(t+1)%DP].  The vmcnt wait at that ds_write is a register dependence on
// loads issued DP-1 iterations earlier -> ~DP full iterations of latency
// coverage (~900+ cyc at DP=3) vs ~300 cyc at the R4 depth-1 pipeline.
// A32/B32: fp32 source, converted to bf16 at ds_write (cvt fused into GEMM).
// LDS fragment order: chunk p = (i*4+q)*16+r holds X[i*16+r][k0+q*8..+7];
// staging writes and ds_read_b128 fragment reads both lane-linear.
template<int NB> struct GemmArgs {
    const void* A[NB];
    const void* B[NB];
    const float* bias[NB];
    void* C[NB];
    int trans[NB];
};

template<int BM, int BN, int DP, int NB, bool A32, bool B32, bool BF16_OUT,
         bool HAS_BIAS, bool ALLOW_TRANS, int MINW>
__global__ __launch_bounds__(256, MINW) void gemm_db(
    GemmArgs<NB> args, int M, int N, int K, float scale)
{
    constexpr int BK = 32;
    constexpr int MI = BM / 32;      // MFMA row tiles per wave (2x2 waves)
    constexpr int MJ = BN / 32;
    constexpr int CA = BM / 64;      // staging chunks per thread
    constexpr int CB = BN / 64;

    __shared__ __align__(16) ushort_t lA[DP][BM * BK];
    __shared__ __align__(16) ushort_t lB[DP][BN * BK];

    const int z = blockIdx.z;
    const char* __restrict__ Ab = (const char*)args.A[z];
    const char* __restrict__ Bb = (const char*)args.B[z];

    const int tid  = threadIdx.x;
    const int lane = tid & 63;
    const int wave = tid >> 6;
    const int wm   = wave >> 1;
    const int wn   = wave & 1;
    const int quad = lane >> 4;
    const int r16  = lane & 15;

    const int row0 = blockIdx.y * BM;
    const int col0 = blockIdx.x * BN;

    floatx4 acc[MI][MJ] = {};

    // per-chunk global base pointers (byte)
    const char* gA[CA];
    const char* gB[CB];
    #pragma unroll
    for (int c = 0; c < CA; c++) {
        int p = c * 256 + tid;
        int i = p >> 6, q = (p >> 4) & 3, r = p & 15;
        size_t eoff = (size_t)(row0 + i * 16 + r) * K + q * 8;
        gA[c] = Ab + eoff * (A32 ? 4 : 2);
    }
    #pragma unroll
    for (int c = 0; c < CB; c++) {
        int p = c * 256 + tid;
        int i = p >> 6, q = (p >> 4) & 3, r = p & 15;
        size_t eoff = (size_t)(col0 + i * 16 + r) * K + q * 8;
        gB[c] = Bb + eoff * (B32 ? 4 : 2);
    }

    // staging registers: DP sets (indices always compile-time via unroll)
    float4 rAf[DP][CA][2]; uint4 rAu[DP][CA];
    float4 rBf[DP][CB][2]; uint4 rBu[DP][CB];

    auto loadA = [&](int d) {
        #pragma unroll
        for (int c = 0; c < CA; c++) {
            if constexpr (A32) {
                rAf[d][c][0] = *(const float4*)(gA[c]);
                rAf[d][c][1] = *(const float4*)(gA[c] + 16);
                gA[c] += BK * 4;
            } else {
                rAu[d][c] = *(const uint4*)(gA[c]);
                gA[c] += BK * 2;
            }
        }
    };
    auto loadB = [&](int d) {
        #pragma unroll
        for (int c = 0; c < CB; c++) {
            if constexpr (B32) {
                rBf[d][c][0] = *(const float4*)(gB[c]);
                rBf[d][c][1] = *(const float4*)(gB[c] + 16);
                gB[c] += BK * 4;
            } else {
                rBu[d][c] = *(const uint4*)(gB[c]);
                gB[c] += BK * 2;
            }
        }
    };
    auto writeA = [&](int d) {
        #pragma unroll
        for (int c = 0; c < CA; c++) {
            bf16x8 v;
            if constexpr (A32) {
                v[0] = (short)f2bf(rAf[d][c][0].x); v[1] = (short)f2bf(rAf[d][c][0].y);
                v[2] = (short)f2bf(rAf[d][c][0].z); v[3] = (short)f2bf(rAf[d][c][0].w);
                v[4] = (short)f2bf(rAf[d][c][1].x); v[5] = (short)f2bf(rAf[d][c][1].y);
                v[6] = (short)f2bf(rAf[d][c][1].z); v[7] = (short)f2bf(rAf[d][c][1].w);
            } else {
                v = *(const bf16x8*)&rAu[d][c];
            }
            *(bf16x8*)(&lA[d][(c * 256 + tid) * 8]) = v;
        }
    };
    auto writeB = [&](int d) {
        #pragma unroll
        for (int c = 0; c < CB; c++) {
            bf16x8 v;
            if constexpr (B32) {
                v[0] = (short)f2bf(rBf[d][c][0].x); v[1] = (short)f2bf(rBf[d][c][0].y);
                v[2] = (short)f2bf(rBf[d][c][0].z); v[3] = (short)f2bf(rBf[d][c][0].w);
                v[4] = (short)f2bf(rBf[d][c][1].x); v[5] = (short)f2bf(rBf[d][c][1].y);
                v[6] = (short)f2bf(rBf[d][c][1].z); v[7] = (short)f2bf(rBf[d][c][1].w);
            } else {
                v = *(const bf16x8*)&rBu[d][c];
            }
            *(bf16x8*)(&lB[d][(c * 256 + tid) * 8]) = v;
        }
    };

    const int T = K / BK;

    // prologue: tiles 0..DP-1 in flight; tile 0 staged to LDS
    #pragma unroll
    for (int d = 0; d < DP; d++) { loadA(d); loadB(d); }
    writeA(0); writeB(0);
    __syncthreads();

    for (int tb = 0; tb < T; tb += DP) {
        #pragma unroll
        for (int s = 0; s < DP; s++) {
            const int t = tb + s;
            if (t >= T) break;
            if (t + DP < T) { loadA(s); loadB(s); }   // tile t+DP into set s

            bf16x8 af[MI], bfr[MJ];
            #pragma unroll
            for (int i = 0; i < MI; i++)
                af[i] = *(const bf16x8*)(&lA[s][((wm * MI + i) * 64 + lane) * 8]);
            #pragma unroll
            for (int j = 0; j < MJ; j++)
                bfr[j] = *(const bf16x8*)(&lB[s][((wn * MJ + j) * 64 + lane) * 8]);

            #pragma unroll
            for (int i = 0; i < MI; i++)
                #pragma unroll
                for (int j = 0; j < MJ; j++)
                    acc[i][j] = __builtin_amdgcn_mfma_f32_16x16x32_bf16(
                        af[i], bfr[j], acc[i][j], 0, 0, 0);

            constexpr int DNXT = 1;
            const int nxt = (s + DNXT) % DP;
            if (t + 1 < T) { writeA(nxt); writeB(nxt); }  // waits tile t+1 loads
            __syncthreads();
        }
    }

    float bv[MJ];
    if (HAS_BIAS) {
        #pragma unroll
        for (int j = 0; j < MJ; j++)
            bv[j] = args.bias[z][col0 + (wn * MJ + j) * 16 + r16];
    }

    void* C = args.C[z];
    const bool do_trans = ALLOW_TRANS && args.trans[z];

    #pragma unroll
    for (int i = 0; i < MI; i++) {
        const int m_base = row0 + (wm * MI + i) * 16 + quad * 4;
        #pragma unroll
        for (int j = 0; j < MJ; j++) {
            const int n = col0 + (wn * MJ + j) * 16 + r16;
            if (ALLOW_TRANS && do_trans) {
                // C^T layout [N][M], bf16; 4 consecutive m -> one 8B store
                ushort4 o;
                float v0 = acc[i][j][0] * scale; if (HAS_BIAS) v0 += bv[j];
                float v1 = acc[i][j][1] * scale; if (HAS_BIAS) v1 += bv[j];
                float v2 = acc[i][j][2] * scale; if (HAS_BIAS) v2 += bv[j];
                float v3 = acc[i][j][3] * scale; if (HAS_BIAS) v3 += bv[j];
                o.x = f2bf(v0); o.y = f2bf(v1); o.z = f2bf(v2); o.w = f2bf(v3);
                *(ushort4*)((ushort_t*)C + (size_t)n * M + m_base) = o;
            } else {
                #pragma unroll
                for (int r = 0; r < 4; r++) {
                    float v = acc[i][j][r] * scale;
                    if (HAS_BIAS) v += bv[j];
                    size_t off = (size_t)(m_base + r) * N + n;
                    if (BF16_OUT) ((ushort_t*)C)[off] = f2bf(v);
                    else          ((float*)C)[off] = v;
                }
            }
        }
    }
}

// ---------- row softmax, in-place: S[row,0..4095] bf16, fp32 math ----------
struct SmArgs { ushort_t* S[2]; };

__global__ __launch_bounds__(256) void softmax_kernel(SmArgs a) {
    const int N = 4096;
    ushort_t* S = a.S[blockIdx.y];
    const int row = blockIdx.x;
    const int tid = threadIdx.x;
    const int lane = tid & 63;
    const int wave = tid >> 6;

    bf16x8* ptr = (bf16x8*)(S + (size_t)row * N);
    bf16x8 c0 = ptr[2 * tid];
    bf16x8 c1 = ptr[2 * tid + 1];

    float x[16];
    #pragma unroll
    for (int k = 0; k < 8; k++) {
        x[k]     = bf2f((ushort_t)c0[k]);
        x[8 + k] = bf2f((ushort_t)c1[k]);
    }

    float m = -3.4e38f;
    #pragma unroll
    for (int k = 0; k < 16; k++) m = fmaxf(m, x[k]);
    #pragma unroll
    for (int off = 32; off > 0; off >>= 1) m = fmaxf(m, __shfl_xor(m, off));

    __shared__ float redmax[4], redsum[4];
    if (lane == 0) redmax[wave] = m;
    __syncthreads();
    m = fmaxf(fmaxf(redmax[0], redmax[1]), fmaxf(redmax[2], redmax[3]));

    float s = 0.f;
    #pragma unroll
    for (int k = 0; k < 16; k++) { x[k] = __expf(x[k] - m); s += x[k]; }
    #pragma unroll
    for (int off = 32; off > 0; off >>= 1) s += __shfl_xor(s, off);
    if (lane == 0) redsum[wave] = s;
    __syncthreads();
    s = redsum[0] + redsum[1] + redsum[2] + redsum[3];
    const float inv = 1.0f / s;

    bf16x8 o0, o1;
    #pragma unroll
    for (int k = 0; k < 8; k++) {
        o0[k] = (short)f2bf(x[k] * inv);
        o1[k] = (short)f2bf(x[8 + k] * inv);
    }
    ptr[2 * tid]     = o0;
    ptr[2 * tid + 1] = o1;
}

// ---------- launch ----------
extern "C" void kernel_launch(void* const* d_in, const int* in_sizes, int n_in,
                              void* d_out, int out_size, void* d_ws, size_t ws_size,
                              hipStream_t stream) {
    (void)in_sizes; (void)n_in; (void)out_size;
    const int NC = 4096, NP = 4096, D = 1024;

    char* ws = (char*)d_ws;
    size_t off = 0;
    auto alloc = [&](size_t b) { size_t o = off; off += (b + 255) & ~(size_t)255; return o; };

    ushort_t* qc  = (ushort_t*)(ws + alloc((size_t)NC * D * 2));
    ushort_t* kc  = (ushort_t*)(ws + alloc((size_t)NC * D * 2));
    ushort_t* qp  = (ushort_t*)(ws + alloc((size_t)NP * D * 2));
    ushort_t* kp  = (ushort_t*)(ws + alloc((size_t)NP * D * 2));
    ushort_t* vcT = (ushort_t*)(ws + alloc((size_t)NC * D * 2)); // [D][NC]
    ushort_t* vpT = (ushort_t*)(ws + alloc((size_t)NP * D * 2)); // [D][NP]
    ushort_t* Sb1 = (ushort_t*)(ws + alloc((size_t)4096 * 4096 * 2));
    ushort_t* Sb2 = (ushort_t*)(ws + alloc((size_t)4096 * 4096 * 2));

    if (ws_size < off) return;

    const dim3 blk(256);
    const float inv_scale = 1.0f / 32.0f; // 1/sqrt(D_OUT)

    float* out_c = (float*)d_out;                       // comp_fused [NC, D]
    float* out_p = (float*)d_out + (size_t)NC * D;      // prot_fused [NP, D]

    // --- 6 projections, one dispatch: fp32 in (fused cvt), bf16 out, DP=2 ---
    {
        GemmArgs<6> ga;
        ushort_t* outs[6] = {qc, kc, vcT, qp, kp, vpT};
        const int widx[6] = {6, 8, 10, 12, 14, 16};
        const int bidx[6] = {7, 9, 11, 13, 15, 17};
        for (int i = 0; i < 6; i++) {
            ga.A[i] = d_in[i];            // fp32 [4096,1024]
            ga.B[i] = d_in[widx[i]];      // fp32 [1024,1024] (torch layout = B^T)
            ga.bias[i] = (const float*)d_in[bidx[i]];
            ga.C[i] = outs[i];
            ga.trans[i] = (i == 2 || i == 5);   // v projections -> transposed
        }
        gemm_db<128, 128, 2, 6, true, true, true, true, true, 2>
            <<<dim3(D / 128, NC / 128, 6), blk, 0, stream>>>(ga, NC, D, D, 1.0f);
    }

    // --- 2 score GEMMs, one dispatch: bf16, 128x128, DP=3 ---
    {
        GemmArgs<2> ga;
        ga.A[0] = qc; ga.B[0] = kp; ga.C[0] = Sb1;
        ga.A[1] = qp; ga.B[1] = kc; ga.C[1] = Sb2;
        ga.bias[0] = ga.bias[1] = nullptr;
        ga.trans[0] = ga.trans[1] = 0;
        gemm_db<128, 128, 3, 2, false, false, true, false, false, 2>
            <<<dim3(4096 / 128, 4096 / 128, 2), blk, 0, stream>>>(
                ga, 4096, 4096, D, inv_scale);
    }

    // --- 2 softmaxes, one dispatch, in-place ---
    {
        SmArgs sa; sa.S[0] = Sb1; sa.S[1] = Sb2;
        softmax_kernel<<<dim3(4096, 2), blk, 0, stream>>>(sa);
    }

    // --- 2 PV GEMMs, one dispatch: bf16 in, fp32 out, DP=3 ---
    {
        GemmArgs<2> ga;
        ga.A[0] = Sb1; ga.B[0] = vpT; ga.C[0] = out_c;
        ga.A[1] = Sb2; ga.B[1] = vcT; ga.C[1] = out_p;
        ga.bias[0] = ga.bias[1] = nullptr;
        ga.trans[0] = ga.trans[1] = 0;
        gemm_db<128, 128, 3, 2, false, false, false, false, false, 2>
            <<<dim3(D / 128, 4096 / 128, 2), blk, 0, stream>>>(
                ga, 4096, D, 4096, 1.0f);
    }
}

// Round 6
// 561.185 us; speedup vs baseline: 1.3754x; 1.0615x over previous
//
#include <hip/hip_runtime.h>

typedef unsigned short ushort_t;
typedef short bf16x8 __attribute__((ext_vector_type(8)));
typedef float floatx4 __attribute__((ext_vector_type(4)));

// ---------- bf16 helpers (bit-level, RNE) ----------
__device__ __forceinline__ float bf2f(ushort_t u) {
    return __uint_as_float(((unsigned)u) << 16);
}
__device__ __forceinline__ ushort_t f2bf(float f) {
    unsigned u = __float_as_uint(f);
    unsigned rnd = 0x7fffu + ((u >> 16) & 1u);
    return (ushort_t)((u + rnd) >> 16);
}

// ---------- fp32 -> bf16 batch convert ----------
struct CvtArgs {
    const float* src[12];
    ushort_t* dst[12];
    int n4[12];
};

__global__ __launch_bounds__(256) void cvt_kernel(CvtArgs a) {
    int t = blockIdx.y;
    int n4 = a.n4[t];
    const float4* s = (const float4*)a.src[t];
    ushort_t* d = a.dst[t];
    int stride = gridDim.x * blockDim.x;
    for (int i = blockIdx.x * blockDim.x + threadIdx.x; i < n4; i += stride) {
        float4 v = s[i];
        ushort4 o;
        o.x = f2bf(v.x); o.y = f2bf(v.y); o.z = f2bf(v.z); o.w = f2bf(v.w);
        ((ushort4*)d)[i] = o;
    }
}

// ---------- batched bf16 GEMM: C[M,N] = A[M,K] @ B[N,K]^T * scale (+bias) ---
// BK=64: 32 MFMA/wave per staged tile (2 k-substeps) to amortize the
// per-iteration barrier/LDS-round-trip slot (~1000 cyc) over 2x the compute.
// DP-deep pipeline: loads for tile t+DP issue before the MFMA phase on tile t;
// vmcnt wait for tile t+1's loads lands at the ds_write after the MFMAs.
// XCD swizzle: grid launched as (M/BM, N/BN, NB) with row0 = blockIdx.x*BM.
// Blocks sharing A-rows (same x, different y) have linear-index stride
// gridDim.x (multiple of 8) -> same XCD under round-robin dispatch -> A rows
// fetched once per XCD L2 instead of once per column-block.
// LDS fragment order: chunk p = (i*KQ+q)*16+r holds X[i*16+r][k0+q*8..+7];
// staging writes and ds_read_b128 fragment reads are both lane-linear.
template<int NB> struct GemmArgs {
    const ushort_t* A[NB];
    const ushort_t* B[NB];
    const float* bias[NB];
    void* C[NB];
    int trans[NB];
};

template<int BM, int BN, int BK, int DP, int NB, bool BF16_OUT,
         bool HAS_BIAS, bool ALLOW_TRANS, int MINW>
__global__ __launch_bounds__(256, MINW) void gemm_bf16(
    GemmArgs<NB> args, int M, int N, int K, float scale)
{
    constexpr int KQ = BK / 8;            // 8-elem k-chunks per row
    constexpr int NS = BK / 32;           // MFMA k-substeps per staged tile
    constexpr int MI = BM / 32;           // MFMA row tiles per wave (2x2 waves)
    constexpr int MJ = BN / 32;
    constexpr int CA = BM * BK / (8 * 256);   // staging chunks per thread
    constexpr int CB = BN * BK / (8 * 256);

    __shared__ __align__(16) ushort_t lA[DP][BM * BK];
    __shared__ __align__(16) ushort_t lB[DP][BN * BK];

    const int z = blockIdx.z;
    const ushort_t* __restrict__ A = args.A[z];
    const ushort_t* __restrict__ B = args.B[z];

    const int tid  = threadIdx.x;
    const int lane = tid & 63;
    const int wave = tid >> 6;
    const int wm   = wave >> 1;
    const int wn   = wave & 1;
    const int quad = lane >> 4;
    const int r16  = lane & 15;

    const int row0 = blockIdx.x * BM;     // x = M dim (fast) -> XCD swizzle
    const int col0 = blockIdx.y * BN;

    floatx4 acc[MI][MJ] = {};

    const ushort_t* gA[CA];
    const ushort_t* gB[CB];
    #pragma unroll
    for (int c = 0; c < CA; c++) {
        int p = c * 256 + tid;
        int i = p / (16 * KQ), q = (p >> 4) % KQ, r = p & 15;
        gA[c] = A + (size_t)(row0 + i * 16 + r) * K + q * 8;
    }
    #pragma unroll
    for (int c = 0; c < CB; c++) {
        int p = c * 256 + tid;
        int i = p / (16 * KQ), q = (p >> 4) % KQ, r = p & 15;
        gB[c] = B + (size_t)(col0 + i * 16 + r) * K + q * 8;
    }

    uint4 rAu[DP][CA];
    uint4 rBu[DP][CB];

    auto loadA = [&](int d) {
        #pragma unroll
        for (int c = 0; c < CA; c++) { rAu[d][c] = *(const uint4*)gA[c]; gA[c] += BK; }
    };
    auto loadB = [&](int d) {
        #pragma unroll
        for (int c = 0; c < CB; c++) { rBu[d][c] = *(const uint4*)gB[c]; gB[c] += BK; }
    };
    auto writeA = [&](int d) {
        #pragma unroll
        for (int c = 0; c < CA; c++)
            *(bf16x8*)(&lA[d][(c * 256 + tid) * 8]) = *(const bf16x8*)&rAu[d][c];
    };
    auto writeB = [&](int d) {
        #pragma unroll
        for (int c = 0; c < CB; c++)
            *(bf16x8*)(&lB[d][(c * 256 + tid) * 8]) = *(const bf16x8*)&rBu[d][c];
    };

    const int T = K / BK;

    // prologue: tiles 0..DP-1 in flight; tile 0 staged
    #pragma unroll
    for (int d = 0; d < DP; d++) { loadA(d); loadB(d); }
    writeA(0); writeB(0);
    __syncthreads();

    for (int tb = 0; tb < T; tb += DP) {
        #pragma unroll
        for (int s = 0; s < DP; s++) {
            const int t = tb + s;
            if (t + DP < T) { loadA(s); loadB(s); }   // tile t+DP into set s

            #pragma unroll
            for (int ss = 0; ss < NS; ss++) {
                bf16x8 af[MI], bfr[MJ];
                #pragma unroll
                for (int i = 0; i < MI; i++)
                    af[i] = *(const bf16x8*)(&lA[s][
                        (((wm * MI + i) * KQ + ss * 4 + quad) * 16 + r16) * 8]);
                #pragma unroll
                for (int j = 0; j < MJ; j++)
                    bfr[j] = *(const bf16x8*)(&lB[s][
                        (((wn * MJ + j) * KQ + ss * 4 + quad) * 16 + r16) * 8]);

                #pragma unroll
                for (int i = 0; i < MI; i++)
                    #pragma unroll
                    for (int j = 0; j < MJ; j++)
                        acc[i][j] = __builtin_amdgcn_mfma_f32_16x16x32_bf16(
                            af[i], bfr[j], acc[i][j], 0, 0, 0);
            }

            const int nxt = (s + 1) % DP;
            if (t + 1 < T) { writeA(nxt); writeB(nxt); }  // waits tile t+1 loads
            __syncthreads();
        }
    }

    float bv[MJ];
    if (HAS_BIAS) {
        #pragma unroll
        for (int j = 0; j < MJ; j++)
            bv[j] = args.bias[z][col0 + (wn * MJ + j) * 16 + r16];
    }

    void* C = args.C[z];
    const bool do_trans = ALLOW_TRANS && args.trans[z];

    #pragma unroll
    for (int i = 0; i < MI; i++) {
        const int m_base = row0 + (wm * MI + i) * 16 + quad * 4;
        #pragma unroll
        for (int j = 0; j < MJ; j++) {
            const int n = col0 + (wn * MJ + j) * 16 + r16;
            if (ALLOW_TRANS && do_trans) {
                // C^T layout [N][M], bf16; 4 consecutive m -> one 8B store
                ushort4 o;
                float v0 = acc[i][j][0] * scale; if (HAS_BIAS) v0 += bv[j];
                float v1 = acc[i][j][1] * scale; if (HAS_BIAS) v1 += bv[j];
                float v2 = acc[i][j][2] * scale; if (HAS_BIAS) v2 += bv[j];
                float v3 = acc[i][j][3] * scale; if (HAS_BIAS) v3 += bv[j];
                o.x = f2bf(v0); o.y = f2bf(v1); o.z = f2bf(v2); o.w = f2bf(v3);
                *(ushort4*)((ushort_t*)C + (size_t)n * M + m_base) = o;
            } else {
                #pragma unroll
                for (int r = 0; r < 4; r++) {
                    float v = acc[i][j][r] * scale;
                    if (HAS_BIAS) v += bv[j];
                    size_t off = (size_t)(m_base + r) * N + n;
                    if (BF16_OUT) ((ushort_t*)C)[off] = f2bf(v);
                    else          ((float*)C)[off] = v;
                }
            }
        }
    }
}

// ---------- row softmax, in-place: S[row,0..4095] bf16, fp32 math ----------
struct SmArgs { ushort_t* S[2]; };

__global__ __launch_bounds__(256) void softmax_kernel(SmArgs a) {
    const int N = 4096;
    ushort_t* S = a.S[blockIdx.y];
    const int row = blockIdx.x;
    const int tid = threadIdx.x;
    const int lane = tid & 63;
    const int wave = tid >> 6;

    bf16x8* ptr = (bf16x8*)(S + (size_t)row * N);
    bf16x8 c0 = ptr[2 * tid];
    bf16x8 c1 = ptr[2 * tid + 1];

    float x[16];
    #pragma unroll
    for (int k = 0; k < 8; k++) {
        x[k]     = bf2f((ushort_t)c0[k]);
        x[8 + k] = bf2f((ushort_t)c1[k]);
    }

    float m = -3.4e38f;
    #pragma unroll
    for (int k = 0; k < 16; k++) m = fmaxf(m, x[k]);
    #pragma unroll
    for (int off = 32; off > 0; off >>= 1) m = fmaxf(m, __shfl_xor(m, off));

    __shared__ float redmax[4], redsum[4];
    if (lane == 0) redmax[wave] = m;
    __syncthreads();
    m = fmaxf(fmaxf(redmax[0], redmax[1]), fmaxf(redmax[2], redmax[3]));

    float s = 0.f;
    #pragma unroll
    for (int k = 0; k < 16; k++) { x[k] = __expf(x[k] - m); s += x[k]; }
    #pragma unroll
    for (int off = 32; off > 0; off >>= 1) s += __shfl_xor(s, off);
    if (lane == 0) redsum[wave] = s;
    __syncthreads();
    s = redsum[0] + redsum[1] + redsum[2] + redsum[3];
    const float inv = 1.0f / s;

    bf16x8 o0, o1;
    #pragma unroll
    for (int k = 0; k < 8; k++) {
        o0[k] = (short)f2bf(x[k] * inv);
        o1[k] = (short)f2bf(x[8 + k] * inv);
    }
    ptr[2 * tid]     = o0;
    ptr[2 * tid + 1] = o1;
}

// ---------- launch ----------
extern "C" void kernel_launch(void* const* d_in, const int* in_sizes, int n_in,
                              void* d_out, int out_size, void* d_ws, size_t ws_size,
                              hipStream_t stream) {
    (void)in_sizes; (void)n_in; (void)out_size;
    const int NC = 4096, NP = 4096, D = 1024;

    char* ws = (char*)d_ws;
    size_t off = 0;
    auto alloc = [&](size_t b) { size_t o = off; off += (b + 255) & ~(size_t)255; return o; };

    ushort_t* xb[6];
    for (int i = 0; i < 6; i++) xb[i] = (ushort_t*)(ws + alloc((size_t)NC * D * 2));
    ushort_t* wb[6];
    for (int i = 0; i < 6; i++) wb[i] = (ushort_t*)(ws + alloc((size_t)D * D * 2));
    ushort_t* qc  = (ushort_t*)(ws + alloc((size_t)NC * D * 2));
    ushort_t* kc  = (ushort_t*)(ws + alloc((size_t)NC * D * 2));
    ushort_t* qp  = (ushort_t*)(ws + alloc((size_t)NP * D * 2));
    ushort_t* kp  = (ushort_t*)(ws + alloc((size_t)NP * D * 2));
    ushort_t* vcT = (ushort_t*)(ws + alloc((size_t)NC * D * 2)); // [D][NC]
    ushort_t* vpT = (ushort_t*)(ws + alloc((size_t)NP * D * 2)); // [D][NP]
    ushort_t* Sb1 = (ushort_t*)(ws + alloc((size_t)4096 * 4096 * 2));
    ushort_t* Sb2 = (ushort_t*)(ws + alloc((size_t)4096 * 4096 * 2));

    if (ws_size < off) return;

    // convert inputs + weights to bf16 (one dispatch)
    CvtArgs ca;
    for (int i = 0; i < 6; i++) {
        ca.src[i] = (const float*)d_in[i];
        ca.dst[i] = xb[i];
        ca.n4[i] = NC * D / 4;
    }
    const int widx[6] = {6, 8, 10, 12, 14, 16};
    for (int i = 0; i < 6; i++) {
        ca.src[6 + i] = (const float*)d_in[widx[i]];
        ca.dst[6 + i] = wb[i];
        ca.n4[6 + i] = D * D / 4;
    }
    cvt_kernel<<<dim3(256, 12), 256, 0, stream>>>(ca);

    const dim3 blk(256);
    const float inv_scale = 1.0f / 32.0f; // 1/sqrt(D_OUT)

    float* out_c = (float*)d_out;                       // comp_fused [NC, D]
    float* out_p = (float*)d_out + (size_t)NC * D;      // prot_fused [NP, D]

    // --- 6 projections, one dispatch: bf16, 128x128, BK=64, DP=2 ---
    // grid (M/128, N/128, 6) = (32, 8, 6); x (M) fast -> A-sharing blocks
    // (same x) land on the same XCD (stride 32 % 8 == 0).
    {
        GemmArgs<6> ga;
        ushort_t* outs[6] = {qc, kc, vcT, qp, kp, vpT};
        const int bidx[6] = {7, 9, 11, 13, 15, 17};
        for (int i = 0; i < 6; i++) {
            ga.A[i] = xb[i];
            ga.B[i] = wb[i];
            ga.bias[i] = (const float*)d_in[bidx[i]];
            ga.C[i] = outs[i];
            ga.trans[i] = (i == 2 || i == 5);   // v projections -> transposed
        }
        gemm_bf16<128, 128, 64, 2, 6, true, true, true, 2>
            <<<dim3(NC / 128, D / 128, 6), blk, 0, stream>>>(ga, NC, D, D, 1.0f);
    }

    // --- 2 score GEMMs, one dispatch: bf16, 128x128, BK=64, DP=2 ---
    {
        GemmArgs<2> ga;
        ga.A[0] = qc; ga.B[0] = kp; ga.C[0] = Sb1;
        ga.A[1] = qp; ga.B[1] = kc; ga.C[1] = Sb2;
        ga.bias[0] = ga.bias[1] = nullptr;
        ga.trans[0] = ga.trans[1] = 0;
        gemm_bf16<128, 128, 64, 2, 2, true, false, false, 2>
            <<<dim3(4096 / 128, 4096 / 128, 2), blk, 0, stream>>>(
                ga, 4096, 4096, D, inv_scale);
    }

    // --- 2 softmaxes, one dispatch, in-place ---
    {
        SmArgs sa; sa.S[0] = Sb1; sa.S[1] = Sb2;
        softmax_kernel<<<dim3(4096, 2), blk, 0, stream>>>(sa);
    }

    // --- 2 PV GEMMs, one dispatch: bf16 in, fp32 out, BK=64, DP=2 ---
    {
        GemmArgs<2> ga;
        ga.A[0] = Sb1; ga.B[0] = vpT; ga.C[0] = out_c;
        ga.A[1] = Sb2; ga.B[1] = vcT; ga.C[1] = out_p;
        ga.bias[0] = ga.bias[1] = nullptr;
        ga.trans[0] = ga.trans[1] = 0;
        gemm_bf16<128, 128, 64, 2, 2, false, false, false, 2>
            <<<dim3(4096 / 128, D / 128, 2), blk, 0, stream>>>(
                ga, 4096, D, 4096, 1.0f);
    }
}